// Round 14
// baseline (229.955 us; speedup 1.0000x reference)
//
#include <hip/hip_runtime.h>
#include <hip/hip_bf16.h>

#define NB   1000
#define NPAD 1024
#define TT   15
#define PP   5
#define CI   32
#define CO   32
#define KDIM 9600
#define MDIM 640
#define MPAD 768
#define NCHUNK 300
#define NCOL   20
#define TABN  16384
#define KSTEPS 150            // K-steps of 64
#define WTELEMS 1536000
#define WTRX_BLOCKS 300
#define TAB_BLOCKS (TABN / 256)
#define XSLOTS 6000000        // input ushort8 slots (48M floats / 8)
#define PADSLOTS 144000       // 5p * 24n * 1200
#define XCVT_BLOCKS 24001

typedef __attribute__((ext_vector_type(8))) short          bf16x8;
typedef __attribute__((ext_vector_type(8))) unsigned short ushort8;
typedef __attribute__((ext_vector_type(4))) float          f32x4;

// ---------------- compile-time integer maps ----------------
struct Chunks {
  short ci[NCHUNK]; short l2[NCHUNK]; short t[NCHUNK]; short k2[NCHUNK];
  short xidx[NCHUNK]; short cls[NCHUNK]; int ns[NCHUNK]; int offc[NCHUNK];
};
constexpr Chunks mkchunks() {
  Chunks c{};
  int idx = 0;
  for (int l2 = 0; l2 < 4; ++l2)
    for (int ci = 0; ci < 2; ++ci)
      for (int t = 0; t < TT; ++t)
        for (int k2 = 0; k2 <= l2; ++k2) {
          c.ci[idx] = (short)ci; c.l2[idx] = (short)l2;
          c.t[idx] = (short)t;   c.k2[idx] = (short)k2;
          c.xidx[idx] = (short)(2 * l2 + ci);
          c.cls[idx]  = (short)(l2 * (l2 + 1) / 2 + k2);
          c.ns[idx]   = TT * (l2 + 1) * PP * CI;
          c.offc[idx] = (t * (l2 + 1) + k2) * PP * CI;
          ++idx;
        }
  return c;
}
__constant__ Chunks g_ck = mkchunks();

struct Cols { int l[NCOL]; int lm[NCOL]; int ci[NCOL]; long obase[NCOL]; };
constexpr Cols mkcols() {
  Cols c{};
  long acc = 0; int idx = 0;
  for (int l = 0; l < 4; ++l)
    for (int ci = 0; ci < 2; ++ci) {
      for (int lm = 0; lm <= l; ++lm) {
        c.l[idx] = l; c.lm[idx] = lm; c.ci[idx] = ci; c.obase[idx] = acc; ++idx;
      }
      acc += (long)NB * (l + 1) * PP * CO;
    }
  return c;
}
__constant__ Cols g_cols = mkcols();

constexpr int wtsize(int tensor) { return ((tensor >> 1) + 1) * TT * PP * CI * CO; }
struct WOffs { int off[8]; int sz[8]; };
constexpr WOffs mkwoffs() {
  WOffs w{}; int acc = 0;
  for (int i = 0; i < 8; ++i) { w.off[i] = acc; w.sz[i] = wtsize(i); acc += w.sz[i]; }
  return w;
}
__constant__ WOffs g_wo = mkwoffs();

__constant__ short g_l1of[10] = {0,1,1,2,2,2,3,3,3,3};
__constant__ short g_mof[10]  = {0,0,1,0,1,2,0,1,2,3};
__constant__ short g_wtT[20] = {0,1,2,2,3,3,4,4,4,5,5,5,6,6,6,6,7,7,7,7};
__constant__ short g_wtM[20] = {0,0,0,1,0,1,0,1,2,0,1,2,0,1,2,3,0,1,2,3};
__constant__ int   g_xslot[9] = {0,300000,600000,1200000,1800000,2700000,3600000,4800000,6000000};
__constant__ short g_cbase[8] = {0,15,30,60,90,135,180,240};

// ---------------- device CG (Racah) in fp64 ----------------
__device__ double dfact(int n) { double r = 1.0; for (int i = 2; i <= n; ++i) r *= i; return r; }

__device__ double dcg(int j1, int m1, int j2, int m2, int J, int M) {
  if (m1 + m2 != M) return 0.0;
  int lo = j1 - j2; if (lo < 0) lo = -lo;
  if (J < lo || J > j1 + j2) return 0.0;
  int am1 = m1 < 0 ? -m1 : m1, am2 = m2 < 0 ? -m2 : m2, aM = M < 0 ? -M : M;
  if (am1 > j1 || am2 > j2 || aM > J) return 0.0;
  double pre = (2.0 * J + 1.0) * dfact(J + j1 - j2) * dfact(J - j1 + j2) * dfact(j1 + j2 - J)
               / dfact(j1 + j2 + J + 1);
  pre *= dfact(J + M) * dfact(J - M) * dfact(j1 - m1) * dfact(j1 + m1) * dfact(j2 - m2) * dfact(j2 + m2);
  double s = 0.0;
  for (int k = 0; k <= j1 + j2 - J; ++k) {
    int d1 = j1 + j2 - J - k, d2 = j1 - m1 - k, d3 = j2 + m2 - k,
        d4 = J - j2 + m1 + k, d5 = J - j1 - m2 + k;
    if (d1 < 0 || d2 < 0 || d3 < 0 || d4 < 0 || d5 < 0) continue;
    double den = dfact(k) * dfact(d1) * dfact(d2) * dfact(d3) * dfact(d4) * dfact(d5);
    s += ((k & 1) ? -1.0 : 1.0) / den;
  }
  return sqrt(pre) * s;
}

// ---------------- wt: weight transpose (LDS) + CG tables ----------------
struct WArgs { const float* w[8]; float* wt; float* tab; };

__global__ __launch_bounds__(256) void k_wt(WArgs A) {
  const int bx = blockIdx.x, tid = threadIdx.x;
  __shared__ float lds[5][32][33];

  if (bx < WTRX_BLOCKS) {
    int t_ = bx % TT;
    int mrow = bx / TT;
    int tensor = g_wtT[mrow], m = g_wtM[mrow];
    const float* src = A.w[tensor] + (size_t)(m * TT + t_) * (PP * CI * CO);
    #pragma unroll
    for (int k = 0; k < 5; ++k) {
      int f = tid + k * 256;
      float4 v = *(const float4*)(src + f * 4);
      int elem = f * 4;
      int p = elem >> 10, rem = elem & 1023;
      int i = rem >> 5, j0 = rem & 31;
      lds[p][i][j0] = v.x; lds[p][i][j0 + 1] = v.y;
      lds[p][i][j0 + 2] = v.z; lds[p][i][j0 + 3] = v.w;
    }
    __syncthreads();
    float* dst = A.wt + g_wo.off[tensor] + (size_t)m * (PP * CO * TT * CI) + t_ * CI;
    #pragma unroll
    for (int k = 0; k < 20; ++k) {
      int e = tid + k * 256;
      int i = e & 31, pj = e >> 5;
      dst[pj * (TT * CI) + i] = lds[pj >> 5][i][pj & 31];
    }
  } else {
    int idx = (bx - WTRX_BLOCKS) * 256 + tid;
    int k2 = idx & 3, m = (idx >> 2) & 3, lm = (idx >> 4) & 3, l2 = (idx >> 6) & 3,
        l1 = (idx >> 8) & 3, l = (idx >> 10) & 3, combo = (idx >> 12) & 3;
    float v = 0.f;
    int dlo = l - l1; if (dlo < 0) dlo = -dlo;
    bool valid = (lm <= l) && (m <= l1) && (k2 <= l2) && (l2 >= dlo) && (l2 <= l + l1);
    if (valid) {
      const double PI = 3.14159265358979323846;
      double coef = 8.0 * PI * PI / (2.0 * l1 + 1.0)
                    * sqrt((2.0 * l + 1.0) * (2.0 * l1 + 1.0) / (4.0 * PI * (2.0 * l2 + 1.0)))
                    * dcg(l, 0, l1, 0, l2, 0);
      double t1 = 0.0, t2 = 0.0, t3 = 0.0;
      if (k2 == lm + m)
        t1 = dcg(l, lm, l1, m, l2, k2) * ((m & 1) ? -1.0 : 1.0);
      if (m > 0 && lm - m >= 0 && k2 == lm - m)
        t2 = dcg(l, lm, l1, -m, l2, lm - m) * ((l1 & 1) ? -1.0 : 1.0);
      if (m > 0 && lm - m < 0 && k2 == m - lm)
        t3 = (((m - lm) & 1) ? -1.0 : 1.0) * (((l1 + l2) & 1) ? -1.0 : 1.0)
             * dcg(l, lm, l1, -m, l2, lm - m);
      double r = 0.0;
      if (combo == 0) r =  coef * (t1 + t2 + t3);
      else if (combo == 1) r = -coef * (t1 - t2 + t3);
      else if (combo == 2) r =  coef * (t1 - t2 - t3);
      else r = coef * (t1 + t2 - t3);
      v = (float)r;
    }
    A.tab[idx] = v;
  }
}

// ---------------- xcvt: input-linear walk -> Xb bf16 (coalesced reads) ----------------
struct XArgs { const float* x[8]; unsigned short* xb; };

__global__ __launch_bounds__(256) void k_xcvt(XArgs A) {
  int g = blockIdx.x * 256 + threadIdx.x;
  if (g >= XSLOTS) {
    int g2 = g - XSLOTS;
    if (g2 >= PADSLOTS) return;
    int pi = g2 % 1200;
    int rest = g2 / 1200;
    int n = 1000 + rest % 24, p = rest / 24;
    ushort8 z = {0,0,0,0,0,0,0,0};
    *(ushort8*)(A.xb + ((size_t)(p * NPAD + n)) * KDIM + pi * 8) = z;
    return;
  }
  int tensor = 0;
  #pragma unroll
  for (int q = 1; q < 8; ++q) if (g >= g_xslot[q]) tensor = q;
  int le = g - g_xslot[tensor];
  int l2 = tensor >> 1;
  int i8 = le & 3;
  int rem = le >> 2;               // [n][t][comps][p]
  int p = rem % PP;
  int rem2 = rem / PP;
  int k2, rem3;
  switch (l2) {
    case 0:  k2 = 0;          rem3 = rem2;      break;
    case 1:  k2 = rem2 & 1;   rem3 = rem2 >> 1; break;
    case 2:  k2 = rem2 % 3;   rem3 = rem2 / 3;  break;
    default: k2 = rem2 & 3;   rem3 = rem2 >> 2; break;
  }
  int t = rem3 % TT;
  int n = rem3 / TT;
  int chunk = g_cbase[tensor] + t * (l2 + 1) + k2;

  const float* src = A.x[tensor] + (size_t)le * 8;
  float4 a = *(const float4*)src;
  float4 b = *(const float4*)(src + 4);
  float fa[8] = {a.x, a.y, a.z, a.w, b.x, b.y, b.z, b.w};
  ushort8 o;
  #pragma unroll
  for (int e = 0; e < 8; ++e) {
    unsigned u = __float_as_uint(fa[e]);
    u += 0x7fff + ((u >> 16) & 1);
    o[e] = (unsigned short)(u >> 16);
  }
  *(ushort8*)(A.xb + ((size_t)(p * NPAD + n)) * KDIM + chunk * 32 + i8 * 8) = o;
}

// ---------------- fold: W_effT[p][mo][k] bf16, LDS-staged, 8-wide ----------------
struct FArgs { const float* wt; const float* tab; unsigned short* weffT; };

__global__ __launch_bounds__(256) void k_fold(FArgs A) {
  const int tid = threadIdx.x;
  const int mo = blockIdx.x, p = blockIdx.y;
  const int j = mo & 31, col = mo >> 5;
  const int l = g_cols.l[col], lm = g_cols.lm[col], cio = g_cols.ci[col];
  __shared__ float ldsW[2][10][480];
  __shared__ float ldsC[2][10][10];

  for (int e = tid; e < 2 * 10 * 480; e += 256) {
    int ti = e % 480;
    int rowid = e / 480;
    int wci = rowid / 10, r = rowid % 10;
    int l1 = g_l1of[r], m = g_mof[r];
    ldsW[wci][r][ti] = A.wt[g_wo.off[2 * l1 + wci] + m * (PP * CO * TT * CI)
                            + (p * CO + j) * (TT * CI) + ti];
  }
  if (tid < 200) {
    int r = tid % 10, clk = (tid / 10) % 10, ci = tid / 100;
    int l1 = g_l1of[r], m = g_mof[r];
    int l2 = g_l1of[clk], k2 = g_mof[clk];
    int combo = cio * 2 + ci, wci = cio ^ ci;
    float v = 0.f;
    int dlo = l - l1; if (dlo < 0) dlo = -dlo;
    if (l2 >= dlo && l2 <= l + l1 && m <= l1 && k2 <= l2)
      v = A.tab[(((((combo * 4 + l) * 4 + l1) * 4 + l2) * 4 + lm) * 4 + m) * 4 + k2];
    if (wci == 1 && m == 0) v = 0.f;
    ldsC[ci][clk][r] = v;
  }
  __syncthreads();

  unsigned short* dst = A.weffT + ((size_t)(p * MDIM + mo)) * KDIM;
  for (int s = tid; s < KDIM / 8; s += 256) {
    int chunk = s >> 2, i0 = (s & 3) * 8;
    int ci = g_ck.ci[chunk], t = g_ck.t[chunk], cls = g_ck.cls[chunk];
    int wci = cio ^ ci;
    float acc8[8] = {};
    #pragma unroll
    for (int r = 0; r < 10; ++r) {
      float c = ldsC[ci][cls][r];
      const float* wrow = &ldsW[wci][r][t * 32 + i0];
      #pragma unroll
      for (int e = 0; e < 8; ++e) acc8[e] += c * wrow[e];
    }
    ushort8 o;
    #pragma unroll
    for (int e = 0; e < 8; ++e) {
      unsigned u = __float_as_uint(acc8[e]);
      u += 0x7fff + ((u >> 16) & 1);
      o[e] = (unsigned short)(u >> 16);
    }
    *(ushort8*)(dst + s * 8) = o;
  }
}

// ---------------- GEMM: 256x256 tile, 8 waves, dbuf BK=64, counted vmcnt(8) ----------------
__device__ __forceinline__ void gl_lds16(const void* g, void* l) {
  __builtin_amdgcn_global_load_lds(
      (const __attribute__((address_space(1))) unsigned int*)g,
      (__attribute__((address_space(3))) unsigned int*)l, 16, 0, 0);
}

struct GArgs { const unsigned short* xb; const unsigned short* weffT; float* partial; int nsplit; };

__global__ __launch_bounds__(512, 2) void k_gemm(GArgs A) {
  const int tid = threadIdx.x;
  const int lane = tid & 63;
  const int wv = tid >> 6;
  const int wr = wv >> 2;            // 0..1 : 128-row half
  const int wc = wv & 3;             // 0..3 : 64-col slice
  const int NS = A.nsplit;

  // XCD-chunked bijective swizzle: nwg = 60*NS (240 for NS=4), divisible by 8
  const int nwg = 60 * NS;
  const int per = nwg >> 3;
  const int wgid = (blockIdx.x & 7) * per + (blockIdx.x >> 3);
  const int zz = wgid / 12, slot = wgid % 12;    // 12 blocks per (p,sp): 4n x 3m
  const int n0 = (slot & 3) * 256, mo0 = (slot >> 2) * 256;
  const int p = zz / NS, sp = zz % NS;
  const int bsteps = KSTEPS / NS, rem = KSTEPS % NS;
  const int mysteps = bsteps + (sp < rem ? 1 : 0);
  const int sstart = sp * bsteps + (sp < rem ? sp : rem);

  __shared__ __align__(16) unsigned short sA[2][256 * 64];   // 64 KB
  __shared__ __align__(16) unsigned short sB[2][256 * 64];   // 64 KB
  f32x4 acc[8][4] = {};

  int aoff[4];
  #pragma unroll
  for (int u = 0; u < 4; ++u) {
    int s = u * 512 + tid;               // 16B slot 0..2047
    int row = s >> 3;                    // 0..255
    int qs = (s & 7) ^ (row & 7);        // pre-swizzled global slot (rule #21)
    aoff[u] = row * KDIM + qs * 8;
  }
  const unsigned short* xbase = A.xb + (size_t)p * NPAD * KDIM + (size_t)n0 * KDIM + sstart * 64;
  const unsigned short* wbase = A.weffT + (size_t)p * MDIM * KDIM + (size_t)mo0 * KDIM + sstart * 64;

#define STG(BUF, step) {                                                            \
    const unsigned short* xs = xbase + (size_t)(step) * 64;                         \
    const unsigned short* ws = wbase + (size_t)(step) * 64;                         \
    _Pragma("unroll")                                                               \
    for (int u = 0; u < 4; ++u)                                                     \
      gl_lds16(xs + aoff[u], (void*)(&sA[BUF][(u * 512 + tid) * 8]));               \
    _Pragma("unroll")                                                               \
    for (int u = 0; u < 4; ++u)                                                     \
      gl_lds16(ws + aoff[u], (void*)(&sB[BUF][(u * 512 + tid) * 8]));               \
  }

#define CMP(BUF) {                                                                  \
    _Pragma("unroll")                                                               \
    for (int ks = 0; ks < 2; ++ks) {                                                \
      const int q = ks * 4 + (lane >> 4);                                           \
      bf16x8 af[8], bfr[4];                                                         \
      _Pragma("unroll")                                                             \
      for (int m = 0; m < 8; ++m) {                                                 \
        int ra = wr * 128 + m * 16 + (lane & 15);                                   \
        af[m] = *(const bf16x8*)&sA[BUF][ra * 64 + ((q ^ (ra & 7)) << 3)];          \
      }                                                                             \
      _Pragma("unroll")                                                             \
      for (int n = 0; n < 4; ++n) {                                                 \
        int rb = wc * 64 + n * 16 + (lane & 15);                                    \
        bfr[n] = *(const bf16x8*)&sB[BUF][rb * 64 + ((q ^ (rb & 7)) << 3)];         \
      }                                                                             \
      _Pragma("unroll")                                                             \
      for (int m = 0; m < 8; ++m)                                                   \
        _Pragma("unroll")                                                           \
        for (int n = 0; n < 4; ++n)                                                 \
          acc[m][n] = __builtin_amdgcn_mfma_f32_16x16x32_bf16(af[m], bfr[n],        \
                                                              acc[m][n], 0, 0, 0);  \
    }                                                                               \
  }

  STG(0, 0);
  if (mysteps > 1) STG(1, 1);
  for (int t = 0; t < mysteps; ++t) {
    const int cur = t & 1;
    // counted vmcnt: tile t's 8 loads are the oldest; tile t+1's 8 stay in flight
    if (t + 1 < mysteps) asm volatile("s_waitcnt vmcnt(8)" ::: "memory");
    else                 asm volatile("s_waitcnt vmcnt(0)" ::: "memory");
    __builtin_amdgcn_s_barrier();
    asm volatile("" ::: "memory");
    CMP(cur);
    asm volatile("" ::: "memory");
    __builtin_amdgcn_s_barrier();
    asm volatile("" ::: "memory");
    if (t + 2 < mysteps) STG(cur, t + 2);
  }

  // epilogue: store fp32 partial. D: col = lane&15 (mo), row = (lane>>4)*4 + r (n)
  float* pout = A.partial + (size_t)zz * (NPAD * MDIM);
  #pragma unroll
  for (int m = 0; m < 8; ++m) {
    #pragma unroll
    for (int nn = 0; nn < 4; ++nn) {
      int mo = mo0 + wc * 64 + nn * 16 + (lane & 15);
      if (mo < MDIM) {
        #pragma unroll
        for (int r = 0; r < 4; ++r) {
          int n = n0 + wr * 128 + m * 16 + (lane >> 4) * 4 + r;
          pout[(size_t)n * MDIM + mo] = acc[m][nn][r];
        }
      }
    }
  }
#undef STG
#undef CMP
}

// ---------------- reduce + bias + scatter (float4) ----------------
struct RArgs { const float* partial; const float* b[8]; float* out; int nsplit; };

__global__ __launch_bounds__(256) void k_red(RArgs A) {
  int e4 = blockIdx.x * 256 + threadIdx.x;
  if (e4 >= NB * (MDIM / 4) * PP) return;
  int mo4 = e4 % (MDIM / 4);
  int rest = e4 / (MDIM / 4);
  int n = rest % NB;
  int p = rest / NB;
  int mo = mo4 * 4;
  float4 s = make_float4(0.f, 0.f, 0.f, 0.f);
  for (int sp = 0; sp < A.nsplit; ++sp) {
    float4 v = *(const float4*)&A.partial[((size_t)(p * A.nsplit + sp) * NPAD + n) * MDIM + mo];
    s.x += v.x; s.y += v.y; s.z += v.z; s.w += v.w;
  }
  int colid = mo >> 5, j = mo & 31;
  int l = g_cols.l[colid], lmv = g_cols.lm[colid], cio = g_cols.ci[colid];
  long base = g_cols.obase[colid];
  float4 bias = *(const float4*)&A.b[2 * l + cio][(lmv * PP + p) * CO + j];
  if (cio == 1 && lmv == 0) bias = make_float4(0.f, 0.f, 0.f, 0.f);
  float4 o = make_float4(s.x + bias.x, s.y + bias.y, s.z + bias.z, s.w + bias.w);
  *(float4*)&A.out[base + (((size_t)n * (l + 1) + lmv) * PP + p) * CO + j] = o;
}

extern "C" void kernel_launch(void* const* d_in, const int* in_sizes, int n_in,
                              void* d_out, int out_size, void* d_ws, size_t ws_size,
                              hipStream_t stream) {
  float* tab = (float*)d_ws;                                   // 16384 f
  float* wt  = tab + TABN;                                     // 1,536,000 f
  unsigned short* weffT = (unsigned short*)(wt + WTELEMS);     // 30,720,000 u16
  unsigned short* xb    = weffT + (size_t)PP * MDIM * KDIM;    // 49,152,000 u16
  float* partial = (float*)(xb + (size_t)PP * NPAD * KDIM);

  size_t base_bytes = (size_t)TABN * 4 + (size_t)WTELEMS * 4
                    + (size_t)PP * MDIM * KDIM * 2 + (size_t)PP * NPAD * KDIM * 2;
  size_t per_split = (size_t)PP * NPAD * MDIM * 4;             // 13.1 MB
  int NS = 2;                                                   // grid 60*NS must be %8==0
  if (ws_size >= base_bytes + 4 * per_split) NS = 4;

  WArgs wa;
  for (int i = 0; i < 8; ++i) wa.w[i] = (const float*)d_in[8 + i];
  wa.wt = wt; wa.tab = tab;
  k_wt<<<dim3(WTRX_BLOCKS + TAB_BLOCKS), dim3(256), 0, stream>>>(wa);

  XArgs xa;
  for (int i = 0; i < 8; ++i) xa.x[i] = (const float*)d_in[i];
  xa.xb = xb;
  k_xcvt<<<dim3(XCVT_BLOCKS), dim3(256), 0, stream>>>(xa);

  FArgs fa;
  fa.wt = wt; fa.tab = (const float*)tab; fa.weffT = weffT;
  k_fold<<<dim3(MDIM, PP), dim3(256), 0, stream>>>(fa);

  GArgs ga;
  ga.xb = xb; ga.weffT = weffT; ga.partial = partial; ga.nsplit = NS;
  k_gemm<<<dim3(60 * NS), dim3(512), 0, stream>>>(ga);

  RArgs ra;
  ra.partial = partial; ra.out = (float*)d_out; ra.nsplit = NS;
  for (int i = 0; i < 8; ++i) ra.b[i] = (const float*)d_in[16 + i];
  k_red<<<dim3((NB * (MDIM / 4) * PP + 255) / 256), dim3(256), 0, stream>>>(ra);
}

// Round 15
// 217.486 us; speedup vs baseline: 1.0573x; 1.0573x over previous
//
#include <hip/hip_runtime.h>
#include <hip/hip_bf16.h>

#define NB   1000
#define NPAD 1024
#define TT   15
#define PP   5
#define CI   32
#define CO   32
#define KDIM 9600
#define MDIM 640
#define NCHUNK 300
#define NCOL   20
#define TABN  16384
#define KSTEPS 150            // K-steps of 64
#define WTELEMS 1536000
#define WTRX_BLOCKS 300
#define TAB_BLOCKS (TABN / 256)
#define XSLOTS 6000000        // input ushort8 slots (48M floats / 8)
#define PADSLOTS 144000       // 5p * 24n * 1200
#define XCVT_BLOCKS 24001     // ceil((XSLOTS+PADSLOTS)/256)

typedef __attribute__((ext_vector_type(8))) short          bf16x8;
typedef __attribute__((ext_vector_type(8))) unsigned short ushort8;
typedef __attribute__((ext_vector_type(4))) float          f32x4;

// ---------------- compile-time integer maps ----------------
struct Chunks {
  short ci[NCHUNK]; short l2[NCHUNK]; short t[NCHUNK]; short k2[NCHUNK];
  short xidx[NCHUNK]; short cls[NCHUNK]; int ns[NCHUNK]; int offc[NCHUNK];
};
constexpr Chunks mkchunks() {
  Chunks c{};
  int idx = 0;
  for (int l2 = 0; l2 < 4; ++l2)
    for (int ci = 0; ci < 2; ++ci)
      for (int t = 0; t < TT; ++t)
        for (int k2 = 0; k2 <= l2; ++k2) {
          c.ci[idx] = (short)ci; c.l2[idx] = (short)l2;
          c.t[idx] = (short)t;   c.k2[idx] = (short)k2;
          c.xidx[idx] = (short)(2 * l2 + ci);
          c.cls[idx]  = (short)(l2 * (l2 + 1) / 2 + k2);
          c.ns[idx]   = TT * (l2 + 1) * PP * CI;
          c.offc[idx] = (t * (l2 + 1) + k2) * PP * CI;
          ++idx;
        }
  return c;
}
__constant__ Chunks g_ck = mkchunks();

struct Cols { int l[NCOL]; int lm[NCOL]; int ci[NCOL]; long obase[NCOL]; };
constexpr Cols mkcols() {
  Cols c{};
  long acc = 0; int idx = 0;
  for (int l = 0; l < 4; ++l)
    for (int ci = 0; ci < 2; ++ci) {
      for (int lm = 0; lm <= l; ++lm) {
        c.l[idx] = l; c.lm[idx] = lm; c.ci[idx] = ci; c.obase[idx] = acc; ++idx;
      }
      acc += (long)NB * (l + 1) * PP * CO;
    }
  return c;
}
__constant__ Cols g_cols = mkcols();

constexpr int wtsize(int tensor) { return ((tensor >> 1) + 1) * TT * PP * CI * CO; }
struct WOffs { int off[8]; int sz[8]; };
constexpr WOffs mkwoffs() {
  WOffs w{}; int acc = 0;
  for (int i = 0; i < 8; ++i) { w.off[i] = acc; w.sz[i] = wtsize(i); acc += w.sz[i]; }
  return w;
}
__constant__ WOffs g_wo = mkwoffs();

__constant__ short g_l1of[10] = {0,1,1,2,2,2,3,3,3,3};
__constant__ short g_mof[10]  = {0,0,1,0,1,2,0,1,2,3};
__constant__ short g_wtT[20] = {0,1,2,2,3,3,4,4,4,5,5,5,6,6,6,6,7,7,7,7};
__constant__ short g_wtM[20] = {0,0,0,1,0,1,0,1,2,0,1,2,0,1,2,3,0,1,2,3};
__constant__ int   g_xslot[9] = {0,300000,600000,1200000,1800000,2700000,3600000,4800000,6000000};
__constant__ short g_cbase[8] = {0,15,30,60,90,135,180,240};

// ---------------- device CG (Racah) in fp64 ----------------
__device__ double dfact(int n) { double r = 1.0; for (int i = 2; i <= n; ++i) r *= i; return r; }

__device__ double dcg(int j1, int m1, int j2, int m2, int J, int M) {
  if (m1 + m2 != M) return 0.0;
  int lo = j1 - j2; if (lo < 0) lo = -lo;
  if (J < lo || J > j1 + j2) return 0.0;
  int am1 = m1 < 0 ? -m1 : m1, am2 = m2 < 0 ? -m2 : m2, aM = M < 0 ? -M : M;
  if (am1 > j1 || am2 > j2 || aM > J) return 0.0;
  double pre = (2.0 * J + 1.0) * dfact(J + j1 - j2) * dfact(J - j1 + j2) * dfact(j1 + j2 - J)
               / dfact(j1 + j2 + J + 1);
  pre *= dfact(J + M) * dfact(J - M) * dfact(j1 - m1) * dfact(j1 + m1) * dfact(j2 - m2) * dfact(j2 + m2);
  double s = 0.0;
  for (int k = 0; k <= j1 + j2 - J; ++k) {
    int d1 = j1 + j2 - J - k, d2 = j1 - m1 - k, d3 = j2 + m2 - k,
        d4 = J - j2 + m1 + k, d5 = J - j1 - m2 + k;
    if (d1 < 0 || d2 < 0 || d3 < 0 || d4 < 0 || d5 < 0) continue;
    double den = dfact(k) * dfact(d1) * dfact(d2) * dfact(d3) * dfact(d4) * dfact(d5);
    s += ((k & 1) ? -1.0 : 1.0) / den;
  }
  return sqrt(pre) * s;
}

// ---------------- prep: xcvt (input-linear) + weight transpose (4.2KB LDS) + tables ----------------
struct PArgs { const float* w[8]; const float* x[8]; float* wt; float* tab; unsigned short* xb; };

__global__ __launch_bounds__(256) void k_prep(PArgs A) {
  const int bx = blockIdx.x, tid = threadIdx.x;
  __shared__ float lds2[32][33];   // 4.2 KB — wt path only; keeps xcvt at 8 blocks/CU

  if (bx < XCVT_BLOCKS) {
    // ---- xcvt: one ushort8 per thread, fully coalesced reads ----
    int g = bx * 256 + tid;
    if (g >= XSLOTS) {
      int g2 = g - XSLOTS;
      if (g2 >= PADSLOTS) return;
      int pi = g2 % 1200;
      int rest = g2 / 1200;
      int n = 1000 + rest % 24, p = rest / 24;
      ushort8 z = {0,0,0,0,0,0,0,0};
      *(ushort8*)(A.xb + ((size_t)(p * NPAD + n)) * KDIM + pi * 8) = z;
      return;
    }
    int tensor = 0;
    #pragma unroll
    for (int q = 1; q < 8; ++q) if (g >= g_xslot[q]) tensor = q;
    int le = g - g_xslot[tensor];
    int l2 = tensor >> 1;
    int i8 = le & 3;
    int rem = le >> 2;               // [n][t][comps][p]
    int p = rem % PP;
    int rem2 = rem / PP;
    int k2, rem3;
    switch (l2) {
      case 0:  k2 = 0;          rem3 = rem2;      break;
      case 1:  k2 = rem2 & 1;   rem3 = rem2 >> 1; break;
      case 2:  k2 = rem2 % 3;   rem3 = rem2 / 3;  break;
      default: k2 = rem2 & 3;   rem3 = rem2 >> 2; break;
    }
    int t = rem3 % TT;
    int n = rem3 / TT;
    int chunk = g_cbase[tensor] + t * (l2 + 1) + k2;

    const float* src = A.x[tensor] + (size_t)le * 8;
    float4 a = *(const float4*)src;
    float4 b = *(const float4*)(src + 4);
    float fa[8] = {a.x, a.y, a.z, a.w, b.x, b.y, b.z, b.w};
    ushort8 o;
    #pragma unroll
    for (int e = 0; e < 8; ++e) {
      unsigned u = __float_as_uint(fa[e]);
      u += 0x7fff + ((u >> 16) & 1);
      o[e] = (unsigned short)(u >> 16);
    }
    *(ushort8*)(A.xb + ((size_t)(p * NPAD + n)) * KDIM + chunk * 32 + i8 * 8) = o;
  } else if (bx < XCVT_BLOCKS + WTRX_BLOCKS) {
    // ---- wt: (m,t,p,i,j) -> (m,p,j,t,i), loop over p with a small LDS tile ----
    int b = bx - XCVT_BLOCKS;
    int t_ = b % TT;
    int mrow = b / TT;
    int tensor = g_wtT[mrow], m = g_wtM[mrow];
    const float* src = A.w[tensor] + (size_t)(m * TT + t_) * (PP * CI * CO);
    float* dstb = A.wt + g_wo.off[tensor] + (size_t)m * (PP * CO * TT * CI) + t_ * CI;
    for (int p = 0; p < PP; ++p) {
      float4 v = *(const float4*)(src + p * (CI * CO) + tid * 4);
      int i = tid >> 3, j0 = (tid & 7) * 4;
      lds2[i][j0] = v.x; lds2[i][j0 + 1] = v.y;
      lds2[i][j0 + 2] = v.z; lds2[i][j0 + 3] = v.w;
      __syncthreads();
      #pragma unroll
      for (int k = 0; k < 4; ++k) {
        int e = tid + k * 256;          // 0..1023
        int ii = e & 31, jj = e >> 5;
        dstb[(p * CO + jj) * (TT * CI) + ii] = lds2[ii][jj];
      }
      __syncthreads();
    }
  } else {
    // ---- CG tables ----
    int idx = (bx - XCVT_BLOCKS - WTRX_BLOCKS) * 256 + tid;
    int k2 = idx & 3, m = (idx >> 2) & 3, lm = (idx >> 4) & 3, l2 = (idx >> 6) & 3,
        l1 = (idx >> 8) & 3, l = (idx >> 10) & 3, combo = (idx >> 12) & 3;
    float v = 0.f;
    int dlo = l - l1; if (dlo < 0) dlo = -dlo;
    bool valid = (lm <= l) && (m <= l1) && (k2 <= l2) && (l2 >= dlo) && (l2 <= l + l1);
    if (valid) {
      const double PI = 3.14159265358979323846;
      double coef = 8.0 * PI * PI / (2.0 * l1 + 1.0)
                    * sqrt((2.0 * l + 1.0) * (2.0 * l1 + 1.0) / (4.0 * PI * (2.0 * l2 + 1.0)))
                    * dcg(l, 0, l1, 0, l2, 0);
      double t1 = 0.0, t2 = 0.0, t3 = 0.0;
      if (k2 == lm + m)
        t1 = dcg(l, lm, l1, m, l2, k2) * ((m & 1) ? -1.0 : 1.0);
      if (m > 0 && lm - m >= 0 && k2 == lm - m)
        t2 = dcg(l, lm, l1, -m, l2, lm - m) * ((l1 & 1) ? -1.0 : 1.0);
      if (m > 0 && lm - m < 0 && k2 == m - lm)
        t3 = (((m - lm) & 1) ? -1.0 : 1.0) * (((l1 + l2) & 1) ? -1.0 : 1.0)
             * dcg(l, lm, l1, -m, l2, lm - m);
      double r = 0.0;
      if (combo == 0) r =  coef * (t1 + t2 + t3);
      else if (combo == 1) r = -coef * (t1 - t2 + t3);
      else if (combo == 2) r =  coef * (t1 - t2 - t3);
      else r = coef * (t1 + t2 - t3);
      v = (float)r;
    }
    A.tab[idx] = v;
  }
}

// ---------------- fold: W_effT[p][mo][k] bf16, LDS-staged, 8-wide ----------------
struct FArgs { const float* wt; const float* tab; unsigned short* weffT; };

__global__ __launch_bounds__(256) void k_fold(FArgs A) {
  const int tid = threadIdx.x;
  const int mo = blockIdx.x, p = blockIdx.y;
  const int j = mo & 31, col = mo >> 5;
  const int l = g_cols.l[col], lm = g_cols.lm[col], cio = g_cols.ci[col];
  __shared__ float ldsW[2][10][480];
  __shared__ float ldsC[2][10][10];

  for (int e = tid; e < 2 * 10 * 480; e += 256) {
    int ti = e % 480;
    int rowid = e / 480;
    int wci = rowid / 10, r = rowid % 10;
    int l1 = g_l1of[r], m = g_mof[r];
    ldsW[wci][r][ti] = A.wt[g_wo.off[2 * l1 + wci] + m * (PP * CO * TT * CI)
                            + (p * CO + j) * (TT * CI) + ti];
  }
  if (tid < 200) {
    int r = tid % 10, clk = (tid / 10) % 10, ci = tid / 100;
    int l1 = g_l1of[r], m = g_mof[r];
    int l2 = g_l1of[clk], k2 = g_mof[clk];
    int combo = cio * 2 + ci, wci = cio ^ ci;
    float v = 0.f;
    int dlo = l - l1; if (dlo < 0) dlo = -dlo;
    if (l2 >= dlo && l2 <= l + l1 && m <= l1 && k2 <= l2)
      v = A.tab[(((((combo * 4 + l) * 4 + l1) * 4 + l2) * 4 + lm) * 4 + m) * 4 + k2];
    if (wci == 1 && m == 0) v = 0.f;
    ldsC[ci][clk][r] = v;
  }
  __syncthreads();

  unsigned short* dst = A.weffT + ((size_t)(p * MDIM + mo)) * KDIM;
  for (int s = tid; s < KDIM / 8; s += 256) {
    int chunk = s >> 2, i0 = (s & 3) * 8;
    int ci = g_ck.ci[chunk], t = g_ck.t[chunk], cls = g_ck.cls[chunk];
    int wci = cio ^ ci;
    float acc8[8] = {};
    #pragma unroll
    for (int r = 0; r < 10; ++r) {
      float c = ldsC[ci][cls][r];
      const float* wrow = &ldsW[wci][r][t * 32 + i0];
      #pragma unroll
      for (int e = 0; e < 8; ++e) acc8[e] += c * wrow[e];
    }
    ushort8 o;
    #pragma unroll
    for (int e = 0; e < 8; ++e) {
      unsigned u = __float_as_uint(acc8[e]);
      u += 0x7fff + ((u >> 16) & 1);
      o[e] = (unsigned short)(u >> 16);
    }
    *(ushort8*)(dst + s * 8) = o;
  }
}

// ---------------- GEMM split-K: round-9 exact structure (proven, spill-free) ----------------
__device__ __forceinline__ void gl_lds16(const void* g, void* l) {
  __builtin_amdgcn_global_load_lds(
      (const __attribute__((address_space(1))) unsigned int*)g,
      (__attribute__((address_space(3))) unsigned int*)l, 16, 0, 0);
}

struct GArgs { const unsigned short* xb; const unsigned short* weffT; float* partial; int nsplit; };

__global__ __launch_bounds__(256, 4) void k_gemm(GArgs A) {
  const int tid = threadIdx.x;
  const int lane = tid & 63;
  const int wv = tid >> 6, wr = wv >> 1, wc = wv & 1;
  const int NS = A.nsplit;

  const int x = blockIdx.x & 7;
  const int jj = blockIdx.x >> 3;
  const int perx = 25 * NS;
  const int full = perx / 40;
  int zz, slot;
  if (jj < full * 40) { zz = x + 8 * (jj / 40); slot = jj % 40; }
  else {
    int leftover = perx - full * 40;
    int idx = x * leftover + (jj - full * 40);
    zz = full * 8 + idx / 40; slot = idx % 40;
  }
  const int n0 = (slot & 7) * 128, mo0 = (slot >> 3) * 128;
  const int p = zz / NS, sp = zz % NS;
  const int bsteps = KSTEPS / NS, rem = KSTEPS % NS;
  const int mysteps = bsteps + (sp < rem ? 1 : 0);
  const int sstart = sp * bsteps + (sp < rem ? sp : rem);

  __shared__ __align__(16) unsigned short sA[128 * 64];
  __shared__ __align__(16) unsigned short sB[128 * 64];
  f32x4 acc[4][4] = {};

  int aoff[4];
  #pragma unroll
  for (int u = 0; u < 4; ++u) {
    int s = u * 256 + tid;
    int row = s >> 3;
    int qs = (s & 7) ^ (row & 7);
    aoff[u] = row * KDIM + qs * 8;
  }
  const unsigned short* xbase = A.xb + (size_t)p * NPAD * KDIM + (size_t)n0 * KDIM + sstart * 64;
  const unsigned short* wbase = A.weffT + (size_t)p * MDIM * KDIM + (size_t)mo0 * KDIM + sstart * 64;

  for (int cc = 0; cc < mysteps; ++cc) {
    const unsigned short* xs = xbase + cc * 64;
    const unsigned short* ws = wbase + cc * 64;
    #pragma unroll
    for (int u = 0; u < 4; ++u) {
      gl_lds16(xs + aoff[u], (void*)(sA + (u * 256 + tid) * 8));
      gl_lds16(ws + aoff[u], (void*)(sB + (u * 256 + tid) * 8));
    }
    __syncthreads();
    #pragma unroll
    for (int ks = 0; ks < 2; ++ks) {
      const int q = ks * 4 + (lane >> 4);
      bf16x8 af[4], bfr[4];
      #pragma unroll
      for (int m = 0; m < 4; ++m) {
        int ra = wr * 64 + m * 16 + (lane & 15);
        af[m] = *(const bf16x8*)(sA + ra * 64 + ((q ^ (ra & 7)) << 3));
      }
      #pragma unroll
      for (int n = 0; n < 4; ++n) {
        int rb = wc * 64 + n * 16 + (lane & 15);
        bfr[n] = *(const bf16x8*)(sB + rb * 64 + ((q ^ (rb & 7)) << 3));
      }
      #pragma unroll
      for (int m = 0; m < 4; ++m)
        #pragma unroll
        for (int n = 0; n < 4; ++n)
          acc[m][n] = __builtin_amdgcn_mfma_f32_16x16x32_bf16(af[m], bfr[n], acc[m][n], 0, 0, 0);
    }
    __syncthreads();
  }

  float* pout = A.partial + (size_t)zz * (NPAD * MDIM);
  #pragma unroll
  for (int m = 0; m < 4; ++m) {
    #pragma unroll
    for (int nn = 0; nn < 4; ++nn) {
      int mo = mo0 + wc * 64 + nn * 16 + (lane & 15);
      #pragma unroll
      for (int r = 0; r < 4; ++r) {
        int n = n0 + wr * 64 + m * 16 + (lane >> 4) * 4 + r;
        pout[(size_t)n * MDIM + mo] = acc[m][nn][r];
      }
    }
  }
}

// ---------------- reduce + bias + scatter (float4) ----------------
struct RArgs { const float* partial; const float* b[8]; float* out; int nsplit; };

__global__ __launch_bounds__(256) void k_red(RArgs A) {
  int e4 = blockIdx.x * 256 + threadIdx.x;
  if (e4 >= NB * (MDIM / 4) * PP) return;
  int mo4 = e4 % (MDIM / 4);
  int rest = e4 / (MDIM / 4);
  int n = rest % NB;
  int p = rest / NB;
  int mo = mo4 * 4;
  float4 s = make_float4(0.f, 0.f, 0.f, 0.f);
  for (int sp = 0; sp < A.nsplit; ++sp) {
    float4 v = *(const float4*)&A.partial[((size_t)(p * A.nsplit + sp) * NPAD + n) * MDIM + mo];
    s.x += v.x; s.y += v.y; s.z += v.z; s.w += v.w;
  }
  int colid = mo >> 5, j = mo & 31;
  int l = g_cols.l[colid], lmv = g_cols.lm[colid], cio = g_cols.ci[colid];
  long base = g_cols.obase[colid];
  float4 bias = *(const float4*)&A.b[2 * l + cio][(lmv * PP + p) * CO + j];
  if (cio == 1 && lmv == 0) bias = make_float4(0.f, 0.f, 0.f, 0.f);
  float4 o = make_float4(s.x + bias.x, s.y + bias.y, s.z + bias.z, s.w + bias.w);
  *(float4*)&A.out[base + (((size_t)n * (l + 1) + lmv) * PP + p) * CO + j] = o;
}

extern "C" void kernel_launch(void* const* d_in, const int* in_sizes, int n_in,
                              void* d_out, int out_size, void* d_ws, size_t ws_size,
                              hipStream_t stream) {
  float* tab = (float*)d_ws;                                   // 16384 f
  float* wt  = tab + TABN;                                     // 1,536,000 f
  unsigned short* weffT = (unsigned short*)(wt + WTELEMS);     // 30,720,000 u16
  unsigned short* xb    = weffT + (size_t)PP * MDIM * KDIM;    // 49,152,000 u16
  float* partial = (float*)(xb + (size_t)PP * NPAD * KDIM);

  size_t base_bytes = (size_t)TABN * 4 + (size_t)WTELEMS * 4
                    + (size_t)PP * MDIM * KDIM * 2 + (size_t)PP * NPAD * KDIM * 2;
  size_t per_split = (size_t)PP * NPAD * MDIM * 4;             // 13.1 MB
  int NS = 1;
  const int cands[6] = {8, 6, 5, 4, 3, 2};
  for (int ci = 0; ci < 6; ++ci)
    if (ws_size >= base_bytes + (size_t)cands[ci] * per_split) { NS = cands[ci]; break; }

  PArgs pa;
  for (int i = 0; i < 8; ++i) pa.w[i] = (const float*)d_in[8 + i];
  for (int i = 0; i < 8; ++i) pa.x[i] = (const float*)d_in[i];
  pa.wt = wt; pa.tab = tab; pa.xb = xb;
  k_prep<<<dim3(XCVT_BLOCKS + WTRX_BLOCKS + TAB_BLOCKS), dim3(256), 0, stream>>>(pa);

  FArgs fa;
  fa.wt = wt; fa.tab = (const float*)tab; fa.weffT = weffT;
  k_fold<<<dim3(MDIM, PP), dim3(256), 0, stream>>>(fa);

  GArgs ga;
  ga.xb = xb; ga.weffT = weffT; ga.partial = partial; ga.nsplit = NS;
  k_gemm<<<dim3(200 * NS), dim3(256), 0, stream>>>(ga);

  RArgs ra;
  ra.partial = partial; ra.out = (float*)d_out; ra.nsplit = NS;
  for (int i = 0; i < 8; ++i) ra.b[i] = (const float*)d_in[16 + i];
  k_red<<<dim3((NB * (MDIM / 4) * PP + 255) / 256), dim3(256), 0, stream>>>(ra);
}